// Round 14
// baseline (619.225 us; speedup 1.0000x reference)
//
#include <hip/hip_runtime.h>

#define HID 512
#define SLEN 4096
#define NB 8
#define BSROWS (NB*SLEN)     // 32768 rows per direction
#define NLAYER 4
#define CHUNKT 128
#define NCHUNK 32
#define MT256 128            // 256-row M-tiles per direction (BSROWS/256)
#define CGALL 8192           // scan chains total (2 dirs * 8 batches * 512)

typedef float f32x4 __attribute__((ext_vector_type(4)));
typedef unsigned int u32x4 __attribute__((ext_vector_type(4)));

typedef const __attribute__((address_space(1))) unsigned int* gas_u32p;
typedef __attribute__((address_space(3))) unsigned int* las_u32p;

__device__ __forceinline__ float bf2f(unsigned short u){
  union { unsigned int i; float f; } v; v.i = ((unsigned int)u) << 16; return v.f;
}
__device__ __forceinline__ unsigned short f2bf(float f){
  union { float f; unsigned int i; } v; v.f = f;
  unsigned int u = v.i;
  u = u + 0x7fffu + ((u >> 16) & 1u);
  return (unsigned short)(u >> 16);
}
__device__ __forceinline__ void mfma_bf16(f32x4& acc, u32x4 a, u32x4 b){
  asm("v_mfma_f32_16x16x32_bf16 %0, %1, %2, %0" : "+v"(acc) : "v"(a), "v"(b));
}
// MFMA D-write -> VALU read hazard fence (inline asm is opaque to the
// hazard recognizer; CDNA has no HW interlock here).
__device__ __forceinline__ void mfma_fence(){
  __builtin_amdgcn_sched_barrier(0);
  asm volatile("s_nop 7\n\ts_nop 7\n\ts_nop 7\n\ts_nop 7");
  __builtin_amdgcn_sched_barrier(0);
}
__device__ __forceinline__ void decode_ab(unsigned int v, float& a, float& b){
  a = (float)(v & 0xffffu) * (1.f/65535.f);
  b = fmaf((float)(v >> 16), 2.f/65535.f, -1.f);
}
__device__ __forceinline__ void gload_lds16(const unsigned short* g, unsigned short* l){
  __builtin_amdgcn_global_load_lds((gas_u32p)(const void*)g, (las_u32p)(void*)l, 16, 0, 0);
}
// scan-LDS index with bank-conflict-breaking band swizzle
__device__ __forceinline__ int scidx(int row, int col){
  return row*64 + (col ^ (((row>>2)&3)<<4));
}

// ---------------- prep (gate W + fusion W + x bf16-cast) in ONE dispatch ----------------

__global__ __launch_bounds__(256) void prep_all(
    const float* __restrict__ wzf, const float* __restrict__ whf,
    const float* __restrict__ wzb, const float* __restrict__ whb,
    const float* __restrict__ fw,  const float* __restrict__ x,
    unsigned short* __restrict__ wbf, unsigned short* __restrict__ outw,
    unsigned short* __restrict__ X0)
{
  int idx = blockIdx.x*256 + threadIdx.x;   // 524288 + 65536 + 2097152 = 2686976
  const float* p;
  unsigned short* q;
  if (idx < 524288){
    int i8  = idx & 63;
    int o   = (idx >> 6) & 511;
    int m   = (idx >> 15) & 1;
    int l   = (idx >> 16) & 3;
    int dir = idx >> 18;
    const float* src = dir ? (m ? whb : wzb) : (m ? whf : wzf);
    p = src + ((size_t)(l*512 + o)*512 + i8*8);
    q = wbf + ((((size_t)(dir*4 + l)*2 + m)*512 + o)*512 + i8*8);
  } else if (idx < 589824){
    int j = idx - 524288;
    p = fw + (size_t)j*8;
    q = outw + (size_t)j*8;
  } else {
    int j = idx - 589824;                   // 0 .. 2097151
    p = x + (size_t)j*8;
    q = X0 + (size_t)j*8;
  }
  float4 v0 = *(const float4*)p;
  float4 v1 = *(const float4*)(p+4);
  u32x4 outv;
  outv[0] = (unsigned)f2bf(v0.x) | ((unsigned)f2bf(v0.y)<<16);
  outv[1] = (unsigned)f2bf(v0.z) | ((unsigned)f2bf(v0.w)<<16);
  outv[2] = (unsigned)f2bf(v1.x) | ((unsigned)f2bf(v1.y)<<16);
  outv[3] = (unsigned)f2bf(v1.z) | ((unsigned)f2bf(v1.w)<<16);
  *(u32x4*)q = outv;
}

// ---------------- gate GEMM + in-block chunk scan (both dirs, one dispatch) ----
// Grid: 2048 blocks = 2 dirs x (128 mt x 8 nt). Block: 512 thr (8 waves),
// tile 256 rows x 64 h-cols = TWO 128-row scan chunks (waves 0-3 half 0,
// waves 4-7 half 1). Per-wave geometry, epilogue, scan logic, and all
// downstream layouts are byte-identical to the proven r13 kernel.

__global__ __launch_bounds__(512, 4) void gate_gemm_scan(
    const unsigned short* __restrict__ X,    // full [2*BSROWS][512] bf16
    const unsigned short* __restrict__ Wbf,  // [2][4][2][512][512] bf16
    const float* __restrict__ bzf, const float* __restrict__ bhf,
    const float* __restrict__ bzb, const float* __restrict__ bhb,
    unsigned int* __restrict__ PH0,          // dir0 [BSROWS][512] packed (P,h')
    unsigned int* __restrict__ PH1,          // dir1 (lives in d_out)
    float* __restrict__ Aagg, float* __restrict__ Bagg,
    int layer, int xoff1, int flip1)         // l==0: xoff1=0, flip1=4095
{
  __shared__ __align__(16) unsigned char smem[65536 + 4096];
  unsigned short* As  = (unsigned short*)smem;              // [256][64] bf16 (32K)
  unsigned short* Bzs = (unsigned short*)(smem + 32768);    // [64][64] (8K)
  unsigned short* Bhs = (unsigned short*)(smem + 40960);    // [64][64] (8K)
  unsigned int*   SC  = (unsigned int*)smem;                // [256][64] u32 (64K alias)
  float* SegP = (float*)(smem + 65536);                     // [8][64]
  float* SegH = (float*)(smem + 65536 + 2048);              // [8][64]

  int hw = blockIdx.x;
  int dir = hw >= (MT256*8);
  int hwl = hw - dir*(MT256*8);
  int lg = (hwl & 7)*MT256 + (hwl >> 3);    // XCD-chunked swizzle within half
  int nt  = lg & 7;
  int mt  = lg >> 3;                        // 0..127

  const unsigned short* Xp = X + (size_t)(dir ? xoff1 : 0)*512;
  const int flip = dir ? flip1 : 0;
  const unsigned short* Wz = Wbf + ((size_t)((dir*4 + layer)*2 + 0))*(512*512);
  const unsigned short* Wh = Wbf + ((size_t)((dir*4 + layer)*2 + 1))*(512*512);
  const float* bzp = (dir ? bzb : bzf) + layer*512;
  const float* bhp = (dir ? bhb : bhf) + layer*512;
  unsigned int* PHp = dir ? PH1 : PH0;

  const int tid = threadIdx.x;
  const int lane = tid & 63;
  const int wv = tid >> 6;                  // 0..7
  const int n0 = nt*64;
  const int slot = tid & 7;
  const int rowb = tid >> 3;                // 0..63

  f32x4 accz[2][4], acch[2][4];
  #pragma unroll
  for (int i=0;i<2;++i)
    #pragma unroll
    for (int j=0;j<4;++j){ accz[i][j] = (f32x4)(0.f); acch[i][j] = (f32x4)(0.f); }

  for (int ks=0; ks<8; ++ks){
    int k0 = ks*64;
    #pragma unroll
    for (int it=0; it<4; ++it){
      int row = rowb + it*64;               // 0..255
      int sr = (mt*256 + row) ^ flip;       // batch-local row flip (dir1, layer0)
      u32x4 v = *(const u32x4*)(Xp + (size_t)sr*512 + k0 + slot*8);
      *(u32x4*)(As + row*64 + ((slot ^ (row&7))<<3)) = v;
    }
    {
      int row = rowb;                       // 0..63; 512 thr cover B in one pass
      u32x4 vz = *(const u32x4*)(Wz + (size_t)(n0+row)*512 + k0 + slot*8);
      *(u32x4*)(Bzs + row*64 + ((slot ^ (row&7))<<3)) = vz;
      u32x4 vh = *(const u32x4*)(Wh + (size_t)(n0+row)*512 + k0 + slot*8);
      *(u32x4*)(Bhs + row*64 + ((slot ^ (row&7))<<3)) = vh;
    }
    __syncthreads();
    #pragma unroll
    for (int kk=0; kk<2; ++kk){
      int kslot = kk*4 + (lane >> 4);
      u32x4 af[2];
      #pragma unroll
      for (int mf=0; mf<2; ++mf){
        int row = wv*32 + mf*16 + (lane & 15);
        af[mf] = *(const u32x4*)(As + row*64 + ((kslot ^ (row&7))<<3));
      }
      #pragma unroll
      for (int nf=0; nf<4; ++nf){
        int row = nf*16 + (lane & 15);
        u32x4 bz = *(const u32x4*)(Bzs + row*64 + ((kslot ^ (row&7))<<3));
        u32x4 bh = *(const u32x4*)(Bhs + row*64 + ((kslot ^ (row&7))<<3));
        #pragma unroll
        for (int mf=0; mf<2; ++mf){
          mfma_bf16(accz[mf][nf], af[mf], bz);
          mfma_bf16(acch[mf][nf], af[mf], bh);
        }
      }
    }
    __syncthreads();
  }
  mfma_fence();

  // ---- epilogue: gates -> packed fixed-point (a,b) into LDS (band-swizzled) ----
  // a = 1 - sigmoid(zp) = rcp(1 + exp2(log2e*zp)); th = 1 - 2*rcp(1+exp2(2*log2e*hp)).
  const float C1 = 1.44269504f;   // log2(e)
  const float C2 = 2.88539008f;   // 2*log2(e)
  #pragma unroll
  for (int nf=0; nf<4; ++nf){
    int colL = nf*16 + (lane & 15);
    float bz = bzp[n0 + colL];
    float bh = bhp[n0 + colL];
    #pragma unroll
    for (int mf=0; mf<2; ++mf){
      int rloc = wv*32 + mf*16 + ((lane>>4)<<2);
      #pragma unroll
      for (int r=0; r<4; ++r){
        float zp = accz[mf][nf][r] + bz;
        float hp = acch[mf][nf][r] + bh;
        float a  = __builtin_amdgcn_rcpf(1.f + __builtin_amdgcn_exp2f(C1*zp));
        float th = fmaf(-2.f, __builtin_amdgcn_rcpf(1.f + __builtin_amdgcn_exp2f(C2*hp)), 1.f);
        a = fminf(fmaxf(a, 1e-8f), 1.0f);   // ref clip hi = 1-1e-8, rounds to 1.0f
        float bv = fmaf(-a, th, th);         // (1-a)*th = sigmoid(zp)*tanh(hp)
        unsigned aq = (unsigned)fmaf(a, 65535.f, 0.5f);
        unsigned bq = (unsigned)fmaf(bv, 32767.5f, 32768.0f);
        SC[scidx(rloc + r, colL)] = aq | (bq << 16);
      }
    }
  }
  __syncthreads();

  // ---- pass 1: decode once into registers, per-segment aggregates ----
  // Two independent 128-row chunks: half = seg>>2 (waves 0-3 / 4-7).
  const int col = tid & 63;
  const int seg = tid >> 6;       // == wave id (0..7), uniform per wave
  const int half = seg >> 2;      // chunk half within the 256-row tile
  const int rbase = half*128 + (seg & 3)*32;
  float ar[32], br[32];           // fully-unrolled static indexing (no scratch)
  {
    float P = 1.f, Hl = 0.f;
    #pragma unroll
    for (int r=0; r<32; ++r){
      float a, b; decode_ab(SC[scidx(rbase + r, col)], a, b);
      ar[r] = a; br[r] = b;
      Hl = fmaf(a, Hl, b);
      P *= a;
    }
    SegP[seg*64 + col] = P;
    SegH[seg*64 + col] = Hl;
  }
  __syncthreads();

  // ---- segment prefixes within each half (<=3 serial combines) ----
  float Ppre = 1.f, Hpre = 0.f;
  for (int j = half*4; j < seg; ++j){
    Hpre = fmaf(SegP[j*64 + col], Hpre, SegH[j*64 + col]);
    Ppre *= SegP[j*64 + col];
  }

  // ---- pass 2: rescan from registers, fuse prefix, write (P,h') + aggregates ----
  const int growbase = mt*256 + rbase;
  float pl = 1.f, hl = 0.f;
  float Pg = 1.f, Hg = 0.f;
  #pragma unroll
  for (int r=0; r<32; ++r){
    hl = fmaf(ar[r], hl, br[r]);
    pl *= ar[r];
    Pg = Ppre * pl;
    Hg = fmaf(pl, Hpre, hl);
    unsigned pq = (unsigned)fmaf(Pg, 65535.f, 0.5f);
    PHp[(size_t)(growbase + r)*512 + n0 + col] = pq | ((unsigned)f2bf(Hg) << 16);
  }
  if ((seg & 3) == 3){
    int cg = mt*2 + half;                              // 128-row chunk idx in dir
    int chain = dir*4096 + (cg >> 5)*512 + n0 + col;   // (dir*8+b)*512 + h
    int c = cg & 31;                                   // chunk within sequence
    Aagg[c*CGALL + chain] = Pg;
    Bagg[c*CGALL + chain] = Hg;
  }
}

// ---------------- cross-chunk combine (tiny) ----------------

__global__ __launch_bounds__(256) void scan_p2(
    const float* __restrict__ Aagg, const float* __restrict__ Bagg,
    float* __restrict__ Hin)
{
  int chain = blockIdx.x*256 + threadIdx.x;  // CGALL threads
  float hv = 0.f;
  #pragma unroll
  for (int c=0; c<NCHUNK; ++c){
    Hin[c*CGALL + chain] = hv;
    hv = fmaf(Aagg[c*CGALL + chain], hv, Bagg[c*CGALL + chain]);
  }
}

// ---------------- h reconstruction + residual + LayerNorm (in-place X) ----------------
// One dispatch covers both dirs (65536 tokens); PH split across two buffers.

__global__ __launch_bounds__(256) void recon_ln(
    const unsigned int* __restrict__ PH0,
    const unsigned int* __restrict__ PH1,
    const float* __restrict__ Hin,           // [32][CGALL]
    unsigned short* __restrict__ Xio,        // full [2*BSROWS][512] bf16 in/out
    const float* __restrict__ g, const float* __restrict__ bta, int resid)
{
  int token = blockIdx.x*4 + (threadIdx.x >> 6);   // 0..65535
  int lane = threadIdx.x & 63;
  int dir  = token >> 15;
  int tloc = token & (BSROWS-1);
  const unsigned int* PHp = dir ? PH1 : PH0;
  size_t pbase = (size_t)tloc*512 + lane*8;
  u32x4 p0 = *(const u32x4*)(PHp + pbase);
  u32x4 p1 = *(const u32x4*)(PHp + pbase + 4);
  int c = (tloc >> 7) & 31;
  const float* hin = Hin + (size_t)c*CGALL + (token >> 12)*512 + lane*8;
  f32x4 h0 = *(const f32x4*)hin;
  f32x4 h1 = *(const f32x4*)(hin + 4);
  float v[8];
  #pragma unroll
  for (int j=0; j<4; ++j){
    v[j]   = fmaf((float)(p0[j] & 0xffffu)*(1.f/65535.f), h0[j], bf2f((unsigned short)(p0[j] >> 16)));
    v[4+j] = fmaf((float)(p1[j] & 0xffffu)*(1.f/65535.f), h1[j], bf2f((unsigned short)(p1[j] >> 16)));
  }
  size_t base = (size_t)token*512 + lane*8;
  if (resid){
    u32x4 xv = *(const u32x4*)(Xio + base);
    #pragma unroll
    for (int w=0; w<4; ++w){
      v[2*w]   += bf2f((unsigned short)(xv[w] & 0xffffu));
      v[2*w+1] += bf2f((unsigned short)(xv[w] >> 16));
    }
  }
  float s = 0.f, s2 = 0.f;
  #pragma unroll
  for (int j=0; j<8; ++j){ s += v[j]; s2 += v[j]*v[j]; }
  #pragma unroll
  for (int o=1; o<64; o<<=1){ s += __shfl_xor(s, o, 64); s2 += __shfl_xor(s2, o, 64); }
  float mu = s * (1.f/512.f);
  float var = s2 * (1.f/512.f) - mu*mu;
  float inv = rsqrtf(var + 1e-5f);
  float4 g0 = *(const float4*)(g + lane*8);
  float4 g1 = *(const float4*)(g + lane*8 + 4);
  float4 b0 = *(const float4*)(bta + lane*8);
  float4 b1 = *(const float4*)(bta + lane*8 + 4);
  float gg[8]  = {g0.x,g0.y,g0.z,g0.w,g1.x,g1.y,g1.z,g1.w};
  float bbv[8] = {b0.x,b0.y,b0.z,b0.w,b1.x,b1.y,b1.z,b1.w};
  u32x4 outv;
  #pragma unroll
  for (int w=0; w<4; ++w){
    float y0 = (v[2*w]   - mu)*inv*gg[2*w]   + bbv[2*w];
    float y1 = (v[2*w+1] - mu)*inv*gg[2*w+1] + bbv[2*w+1];
    outv[w] = (unsigned)f2bf(y0) | ((unsigned)f2bf(y1) << 16);
  }
  *(u32x4*)(Xio + base) = outv;
}

// ---------------- fusion GEMM: out = [fwd, flip(bwd)] @ Wf^T + fb ----------------

__global__ __launch_bounds__(256, 4) void fusion_gemm(
    const unsigned short* __restrict__ Xf,   // [2*BSROWS][512] final LN outputs
    const unsigned short* __restrict__ Wf,   // [512][1024] bf16
    const float* __restrict__ fb,
    float* __restrict__ outp)
{
  __shared__ __align__(16) unsigned short As[128*64];
  __shared__ __align__(16) unsigned short Bs[64*64];

  int hw = blockIdx.x;
  int lg = (hw & 7)*256 + (hw >> 3);   // 2048 blocks
  int nt = lg & 7;
  int mt = lg >> 3;                    // 0..255

  const int tid = threadIdx.x;
  const int lane = tid & 63;
  const int wv = tid >> 6;
  const int n0 = nt*64;
  const int lrow  = lane >> 3;
  const int slotp = (lane & 7) ^ (lrow & 7);

  f32x4 acc[2][4];
  #pragma unroll
  for (int i=0;i<2;++i)
    #pragma unroll
    for (int j=0;j<4;++j) acc[i][j] = (f32x4)(0.f);

  for (int ks=0; ks<16; ++ks){
    int k0 = ks*64;
    const unsigned short* Abase = Xf + ((k0 >= 512) ? (size_t)BSROWS*512 : 0);
    int kc = k0 & 511;
    int flip = (k0 >= 512) ? 4095 : 0;
    #pragma unroll
    for (int it=0; it<4; ++it){
      int row = it*32 + wv*8 + lrow;
      int sr = (mt*128 + row) ^ flip;        // flip s within batch for bwd half
      gload_lds16(Abase + (size_t)sr*512 + kc + slotp*8,
                  As + (it*32 + wv*8)*64);
    }
    #pragma unroll
    for (int it=0; it<2; ++it){
      int row = it*32 + wv*8 + lrow;
      gload_lds16(Wf + (size_t)(n0 + row)*1024 + k0 + slotp*8,
                  Bs + (it*32 + wv*8)*64);
    }
    __syncthreads();
    #pragma unroll
    for (int kk=0; kk<2; ++kk){
      int kslot = kk*4 + (lane >> 4);
      u32x4 af[2];
      #pragma unroll
      for (int mf=0; mf<2; ++mf){
        int row = wv*32 + mf*16 + (lane & 15);
        af[mf] = *(const u32x4*)(As + row*64 + ((kslot ^ (row&7))<<3));
      }
      #pragma unroll
      for (int nf=0; nf<4; ++nf){
        int row = nf*16 + (lane & 15);
        u32x4 bv = *(const u32x4*)(Bs + row*64 + ((kslot ^ (row&7))<<3));
        #pragma unroll
        for (int mf=0; mf<2; ++mf) mfma_bf16(acc[mf][nf], af[mf], bv);
      }
    }
    __syncthreads();
  }
  mfma_fence();

  #pragma unroll
  for (int nf=0; nf<4; ++nf){
    int col = n0 + nf*16 + (lane & 15);
    float bias = fb[col];
    #pragma unroll
    for (int mf=0; mf<2; ++mf){
      int rb = mt*128 + wv*32 + mf*16 + ((lane>>4)<<2);
      #pragma unroll
      for (int r=0; r<4; ++r)
        outp[(size_t)(rb + r)*512 + col] = acc[mf][nf][r] + bias;
    }
  }
}

// ---------------- launch ----------------

extern "C" void kernel_launch(void* const* d_in, const int* in_sizes, int n_in,
                              void* d_out, int out_size, void* d_ws, size_t ws_size,
                              hipStream_t stream)
{
  (void)in_sizes; (void)n_in; (void)out_size; (void)ws_size;
  const float* x   = (const float*)d_in[0];
  const float* wzf = (const float*)d_in[1];
  const float* bzf = (const float*)d_in[2];
  const float* whf = (const float*)d_in[3];
  const float* bhf = (const float*)d_in[4];
  const float* wzb = (const float*)d_in[5];
  const float* bzb = (const float*)d_in[6];
  const float* whb = (const float*)d_in[7];
  const float* bhb = (const float*)d_in[8];
  const float* fw  = (const float*)d_in[9];
  const float* fbb = (const float*)d_in[10];
  const float* lng = (const float*)d_in[11];
  const float* lnb = (const float*)d_in[12];
  float* outp = (float*)d_out;

  // ws layout (~140 MiB; r2's profile proves ws >= ~171 MiB):
  char* ws = (char*)d_ws;
  size_t o = 0;
  unsigned short* Wbf = (unsigned short*)(ws + o); o += (size_t)16*512*512*2;   // 8 MiB
  unsigned short* Wfb = (unsigned short*)(ws + o); o += (size_t)512*1024*2;     // 1 MiB
  unsigned short* X   = (unsigned short*)(ws + o); o += (size_t)2*BSROWS*512*2; // 64 MiB
  unsigned int*   PH0 = (unsigned int*)  (ws + o); o += (size_t)BSROWS*512*4;   // 64 MiB
  float* Aagg = (float*)(ws + o); o += (size_t)CGALL*NCHUNK*4;                  // 1 MiB
  float* Bagg = (float*)(ws + o); o += (size_t)CGALL*NCHUNK*4;
  float* Hin  = (float*)(ws + o); o += (size_t)CGALL*NCHUNK*4;
  // dir-1 PH lives in d_out (exactly BSROWS*512*4 = 64 MiB); fully
  // overwritten before any read each call; fusion writes final out last.
  unsigned int* PH1 = (unsigned int*)d_out;

  prep_all<<<10496, 256, 0, stream>>>(wzf, whf, wzb, whb, fw, x, Wbf, Wfb, X);

  for (int l = 0; l < NLAYER; ++l){
    // l==0: both dirs read the pristine dir-0 panel (dir1 row-flipped).
    int xoff1 = (l == 0) ? 0 : BSROWS;
    int flip1 = (l == 0) ? 4095 : 0;
    gate_gemm_scan<<<2048, 512, 0, stream>>>(X, Wbf, bzf, bhf, bzb, bhb,
                                             PH0, PH1, Aagg, Bagg, l, xoff1, flip1);
    scan_p2 <<<CGALL/256, 256, 0, stream>>>(Aagg, Bagg, Hin);
    recon_ln<<<16384, 256, 0, stream>>>(PH0, PH1, Hin, X, lng, lnb, l > 0 ? 1 : 0);
  }

  fusion_gemm<<<2048, 256, 0, stream>>>(X, Wfb, fbb, outp);
}

// Round 15
// 598.158 us; speedup vs baseline: 1.0352x; 1.0352x over previous
//
#include <hip/hip_runtime.h>

#define HID 512
#define SLEN 4096
#define NB 8
#define BSROWS (NB*SLEN)     // 32768 rows per direction
#define NLAYER 4
#define CHUNKT 128
#define NCHUNK 32
#define MTPD 256             // M-tiles per direction (BSROWS/128)
#define CGALL 8192           // scan chains total (2 dirs * 8 batches * 512)

typedef float f32x4 __attribute__((ext_vector_type(4)));
typedef unsigned int u32x4 __attribute__((ext_vector_type(4)));

typedef const __attribute__((address_space(1))) unsigned int* gas_u32p;
typedef __attribute__((address_space(3))) unsigned int* las_u32p;

__device__ __forceinline__ float bf2f(unsigned short u){
  union { unsigned int i; float f; } v; v.i = ((unsigned int)u) << 16; return v.f;
}
__device__ __forceinline__ unsigned short f2bf(float f){
  union { float f; unsigned int i; } v; v.f = f;
  unsigned int u = v.i;
  u = u + 0x7fffu + ((u >> 16) & 1u);
  return (unsigned short)(u >> 16);
}
__device__ __forceinline__ void mfma_bf16(f32x4& acc, u32x4 a, u32x4 b){
  asm("v_mfma_f32_16x16x32_bf16 %0, %1, %2, %0" : "+v"(acc) : "v"(a), "v"(b));
}
// MFMA D-write -> VALU read hazard fence (inline asm is opaque to the
// hazard recognizer; CDNA has no HW interlock here).
__device__ __forceinline__ void mfma_fence(){
  __builtin_amdgcn_sched_barrier(0);
  asm volatile("s_nop 7\n\ts_nop 7\n\ts_nop 7\n\ts_nop 7");
  __builtin_amdgcn_sched_barrier(0);
}
__device__ __forceinline__ void decode_ab(unsigned int v, float& a, float& b){
  a = (float)(v & 0xffffu) * (1.f/65535.f);
  b = fmaf((float)(v >> 16), 2.f/65535.f, -1.f);
}
__device__ __forceinline__ void gload_lds16(const unsigned short* g, unsigned short* l){
  __builtin_amdgcn_global_load_lds((gas_u32p)(const void*)g, (las_u32p)(void*)l, 16, 0, 0);
}
// scan-LDS index with bank-conflict-breaking band swizzle
__device__ __forceinline__ int scidx(int row, int col){
  return row*64 + (col ^ (((row>>2)&3)<<4));
}

// ---------------- prep (gate W + fusion W + x bf16-cast) in ONE dispatch ----------------
// Index ranges are block-aligned (524288/256, 589824/256) -> no intra-block
// divergence. x part is a pure linear cast copy (flip handled at l=0 gate).

__global__ __launch_bounds__(256) void prep_all(
    const float* __restrict__ wzf, const float* __restrict__ whf,
    const float* __restrict__ wzb, const float* __restrict__ whb,
    const float* __restrict__ fw,  const float* __restrict__ x,
    unsigned short* __restrict__ wbf, unsigned short* __restrict__ outw,
    unsigned short* __restrict__ X0)
{
  int idx = blockIdx.x*256 + threadIdx.x;   // 524288 + 65536 + 2097152 = 2686976
  const float* p;
  unsigned short* q;
  if (idx < 524288){
    int i8  = idx & 63;
    int o   = (idx >> 6) & 511;
    int m   = (idx >> 15) & 1;
    int l   = (idx >> 16) & 3;
    int dir = idx >> 18;
    const float* src = dir ? (m ? whb : wzb) : (m ? whf : wzf);
    p = src + ((size_t)(l*512 + o)*512 + i8*8);
    q = wbf + ((((size_t)(dir*4 + l)*2 + m)*512 + o)*512 + i8*8);
  } else if (idx < 589824){
    int j = idx - 524288;
    p = fw + (size_t)j*8;
    q = outw + (size_t)j*8;
  } else {
    int j = idx - 589824;                   // 0 .. 2097151
    p = x + (size_t)j*8;
    q = X0 + (size_t)j*8;
  }
  float4 v0 = *(const float4*)p;
  float4 v1 = *(const float4*)(p+4);
  u32x4 outv;
  outv[0] = (unsigned)f2bf(v0.x) | ((unsigned)f2bf(v0.y)<<16);
  outv[1] = (unsigned)f2bf(v0.z) | ((unsigned)f2bf(v0.w)<<16);
  outv[2] = (unsigned)f2bf(v1.x) | ((unsigned)f2bf(v1.y)<<16);
  outv[3] = (unsigned)f2bf(v1.z) | ((unsigned)f2bf(v1.w)<<16);
  *(u32x4*)q = outv;
}

// ---------------- gate GEMM + in-block chunk scan (both dirs, one dispatch) ----
// Grid: 4096 blocks = 2 dirs x (256 mt x 8 nt). Block internals are the r10
// proven 4-wave 128x64 kernel (bf16 staging; rcp/exp2 epilogue; reg-cached
// pass2). VERBATIM r13 — measured 93-95 us, VGPR 64, total 602.7.

__global__ __launch_bounds__(256, 4) void gate_gemm_scan(
    const unsigned short* __restrict__ X,    // full [2*BSROWS][512] bf16
    const unsigned short* __restrict__ Wbf,  // [2][4][2][512][512] bf16
    const float* __restrict__ bzf, const float* __restrict__ bhf,
    const float* __restrict__ bzb, const float* __restrict__ bhb,
    unsigned int* __restrict__ PH0,          // dir0 [BSROWS][512] packed (P,h')
    unsigned int* __restrict__ PH1,          // dir1 (lives in d_out)
    float* __restrict__ Aagg, float* __restrict__ Bagg,
    int layer, int xoff1, int flip1)         // l==0: xoff1=0, flip1=4095
{
  __shared__ __align__(16) unsigned char smem[32768 + 2048];
  unsigned short* As  = (unsigned short*)smem;              // [128][64] bf16
  unsigned short* Bzs = (unsigned short*)(smem + 16384);    // [64][64]
  unsigned short* Bhs = (unsigned short*)(smem + 24576);    // [64][64]
  unsigned int*   SC  = (unsigned int*)smem;                // [128][64] u32 (alias)
  float* SegP = (float*)(smem + 32768);                     // [4][64]
  float* SegH = (float*)(smem + 32768 + 1024);              // [4][64]

  int hw = blockIdx.x;
  int dir = hw >= (MTPD*8);
  int hwl = hw - dir*(MTPD*8);
  int lg = (hwl & 7)*MTPD + (hwl >> 3);     // XCD-chunked swizzle within half
  int nt  = lg & 7;
  int mt  = lg >> 3;                        // 0..255

  const unsigned short* Xp = X + (size_t)(dir ? xoff1 : 0)*512;
  const int flip = dir ? flip1 : 0;
  const unsigned short* Wz = Wbf + ((size_t)((dir*4 + layer)*2 + 0))*(512*512);
  const unsigned short* Wh = Wbf + ((size_t)((dir*4 + layer)*2 + 1))*(512*512);
  const float* bzp = (dir ? bzb : bzf) + layer*512;
  const float* bhp = (dir ? bhb : bhf) + layer*512;
  unsigned int* PHp = dir ? PH1 : PH0;

  const int tid = threadIdx.x;
  const int lane = tid & 63;
  const int wv = tid >> 6;
  const int n0 = nt*64;
  const int slot = tid & 7;
  const int rowb = tid >> 3;

  f32x4 accz[2][4], acch[2][4];
  #pragma unroll
  for (int i=0;i<2;++i)
    #pragma unroll
    for (int j=0;j<4;++j){ accz[i][j] = (f32x4)(0.f); acch[i][j] = (f32x4)(0.f); }

  for (int ks=0; ks<8; ++ks){
    int k0 = ks*64;
    #pragma unroll
    for (int it=0; it<4; ++it){
      int row = rowb + it*32;
      int sr = (mt*128 + row) ^ flip;     // batch-local row flip (dir1, layer0)
      u32x4 v = *(const u32x4*)(Xp + (size_t)sr*512 + k0 + slot*8);
      *(u32x4*)(As + row*64 + ((slot ^ (row&7))<<3)) = v;
    }
    #pragma unroll
    for (int it=0; it<2; ++it){
      int row = rowb + it*32;
      u32x4 vz = *(const u32x4*)(Wz + (size_t)(n0+row)*512 + k0 + slot*8);
      *(u32x4*)(Bzs + row*64 + ((slot ^ (row&7))<<3)) = vz;
      u32x4 vh = *(const u32x4*)(Wh + (size_t)(n0+row)*512 + k0 + slot*8);
      *(u32x4*)(Bhs + row*64 + ((slot ^ (row&7))<<3)) = vh;
    }
    __syncthreads();
    #pragma unroll
    for (int kk=0; kk<2; ++kk){
      int kslot = kk*4 + (lane >> 4);
      u32x4 af[2];
      #pragma unroll
      for (int mf=0; mf<2; ++mf){
        int row = wv*32 + mf*16 + (lane & 15);
        af[mf] = *(const u32x4*)(As + row*64 + ((kslot ^ (row&7))<<3));
      }
      #pragma unroll
      for (int nf=0; nf<4; ++nf){
        int row = nf*16 + (lane & 15);
        u32x4 bz = *(const u32x4*)(Bzs + row*64 + ((kslot ^ (row&7))<<3));
        u32x4 bh = *(const u32x4*)(Bhs + row*64 + ((kslot ^ (row&7))<<3));
        #pragma unroll
        for (int mf=0; mf<2; ++mf){
          mfma_bf16(accz[mf][nf], af[mf], bz);
          mfma_bf16(acch[mf][nf], af[mf], bh);
        }
      }
    }
    __syncthreads();
  }
  mfma_fence();

  // ---- epilogue: gates -> packed fixed-point (a,b) into LDS (band-swizzled) ----
  // a = 1 - sigmoid(zp) = rcp(1 + exp2(log2e*zp)); th = 1 - 2*rcp(1+exp2(2*log2e*hp)).
  const float C1 = 1.44269504f;   // log2(e)
  const float C2 = 2.88539008f;   // 2*log2(e)
  #pragma unroll
  for (int nf=0; nf<4; ++nf){
    int colL = nf*16 + (lane & 15);
    float bz = bzp[n0 + colL];
    float bh = bhp[n0 + colL];
    #pragma unroll
    for (int mf=0; mf<2; ++mf){
      int rloc = wv*32 + mf*16 + ((lane>>4)<<2);
      #pragma unroll
      for (int r=0; r<4; ++r){
        float zp = accz[mf][nf][r] + bz;
        float hp = acch[mf][nf][r] + bh;
        float a  = __builtin_amdgcn_rcpf(1.f + __builtin_amdgcn_exp2f(C1*zp));
        float th = fmaf(-2.f, __builtin_amdgcn_rcpf(1.f + __builtin_amdgcn_exp2f(C2*hp)), 1.f);
        a = fminf(fmaxf(a, 1e-8f), 1.0f);   // ref clip hi = 1-1e-8, rounds to 1.0f
        float bv = fmaf(-a, th, th);         // (1-a)*th = sigmoid(zp)*tanh(hp)
        unsigned aq = (unsigned)fmaf(a, 65535.f, 0.5f);
        unsigned bq = (unsigned)fmaf(bv, 32767.5f, 32768.0f);
        SC[scidx(rloc + r, colL)] = aq | (bq << 16);
      }
    }
  }
  __syncthreads();

  // ---- pass 1: decode once into registers, per-segment aggregates ----
  const int col = tid & 63;
  const int seg = tid >> 6;       // == wave id, uniform per wave
  float ar[32], br[32];           // fully-unrolled static indexing (no scratch)
  {
    float P = 1.f, Hl = 0.f;
    #pragma unroll
    for (int r=0; r<32; ++r){
      float a, b; decode_ab(SC[scidx(seg*32 + r, col)], a, b);
      ar[r] = a; br[r] = b;
      Hl = fmaf(a, Hl, b);
      P *= a;
    }
    SegP[seg*64 + col] = P;
    SegH[seg*64 + col] = Hl;
  }
  __syncthreads();

  // ---- segment prefixes (<=3 serial combines, wave-uniform trip count) ----
  float Ppre = 1.f, Hpre = 0.f;
  for (int j=0; j<seg; ++j){
    Hpre = fmaf(SegP[j*64 + col], Hpre, SegH[j*64 + col]);
    Ppre *= SegP[j*64 + col];
  }

  // ---- pass 2: rescan from registers, fuse prefix, write (P,h') + aggregates ----
  const int rowbase = mt*128;
  float pl = 1.f, hl = 0.f;
  float Pg = 1.f, Hg = 0.f;
  #pragma unroll
  for (int r=0; r<32; ++r){
    hl = fmaf(ar[r], hl, br[r]);
    pl *= ar[r];
    Pg = Ppre * pl;
    Hg = fmaf(pl, Hpre, hl);
    unsigned pq = (unsigned)fmaf(Pg, 65535.f, 0.5f);
    PHp[(size_t)(rowbase + seg*32 + r)*512 + n0 + col] = pq | ((unsigned)f2bf(Hg) << 16);
  }
  if (seg == 3){
    int chain = dir*4096 + (mt >> 5)*512 + n0 + col;   // (dir*8+b)*512 + h
    int c = mt & 31;                                   // chunk within sequence
    Aagg[c*CGALL + chain] = Pg;
    Bagg[c*CGALL + chain] = Hg;
  }
}

// ---------------- cross-chunk combine (tiny) ----------------

__global__ __launch_bounds__(256) void scan_p2(
    const float* __restrict__ Aagg, const float* __restrict__ Bagg,
    float* __restrict__ Hin)
{
  int chain = blockIdx.x*256 + threadIdx.x;  // CGALL threads
  float hv = 0.f;
  #pragma unroll
  for (int c=0; c<NCHUNK; ++c){
    Hin[c*CGALL + chain] = hv;
    hv = fmaf(Aagg[c*CGALL + chain], hv, Bagg[c*CGALL + chain]);
  }
}

// ---------------- h reconstruction + residual + LayerNorm (in-place X) ----------------
// One dispatch covers both dirs (65536 tokens); PH split across two buffers.

__global__ __launch_bounds__(256) void recon_ln(
    const unsigned int* __restrict__ PH0,
    const unsigned int* __restrict__ PH1,
    const float* __restrict__ Hin,           // [32][CGALL]
    unsigned short* __restrict__ Xio,        // full [2*BSROWS][512] bf16 in/out
    const float* __restrict__ g, const float* __restrict__ bta, int resid)
{
  int token = blockIdx.x*4 + (threadIdx.x >> 6);   // 0..65535
  int lane = threadIdx.x & 63;
  int dir  = token >> 15;
  int tloc = token & (BSROWS-1);
  const unsigned int* PHp = dir ? PH1 : PH0;
  size_t pbase = (size_t)tloc*512 + lane*8;
  u32x4 p0 = *(const u32x4*)(PHp + pbase);
  u32x4 p1 = *(const u32x4*)(PHp + pbase + 4);
  int c = (tloc >> 7) & 31;
  const float* hin = Hin + (size_t)c*CGALL + (token >> 12)*512 + lane*8;
  f32x4 h0 = *(const f32x4*)hin;
  f32x4 h1 = *(const f32x4*)(hin + 4);
  float v[8];
  #pragma unroll
  for (int j=0; j<4; ++j){
    v[j]   = fmaf((float)(p0[j] & 0xffffu)*(1.f/65535.f), h0[j], bf2f((unsigned short)(p0[j] >> 16)));
    v[4+j] = fmaf((float)(p1[j] & 0xffffu)*(1.f/65535.f), h1[j], bf2f((unsigned short)(p1[j] >> 16)));
  }
  size_t base = (size_t)token*512 + lane*8;
  if (resid){
    u32x4 xv = *(const u32x4*)(Xio + base);
    #pragma unroll
    for (int w=0; w<4; ++w){
      v[2*w]   += bf2f((unsigned short)(xv[w] & 0xffffu));
      v[2*w+1] += bf2f((unsigned short)(xv[w] >> 16));
    }
  }
  float s = 0.f, s2 = 0.f;
  #pragma unroll
  for (int j=0; j<8; ++j){ s += v[j]; s2 += v[j]*v[j]; }
  #pragma unroll
  for (int o=1; o<64; o<<=1){ s += __shfl_xor(s, o, 64); s2 += __shfl_xor(s2, o, 64); }
  float mu = s * (1.f/512.f);
  float var = s2 * (1.f/512.f) - mu*mu;
  float inv = rsqrtf(var + 1e-5f);
  float4 g0 = *(const float4*)(g + lane*8);
  float4 g1 = *(const float4*)(g + lane*8 + 4);
  float4 b0 = *(const float4*)(bta + lane*8);
  float4 b1 = *(const float4*)(bta + lane*8 + 4);
  float gg[8]  = {g0.x,g0.y,g0.z,g0.w,g1.x,g1.y,g1.z,g1.w};
  float bbv[8] = {b0.x,b0.y,b0.z,b0.w,b1.x,b1.y,b1.z,b1.w};
  u32x4 outv;
  #pragma unroll
  for (int w=0; w<4; ++w){
    float y0 = (v[2*w]   - mu)*inv*gg[2*w]   + bbv[2*w];
    float y1 = (v[2*w+1] - mu)*inv*gg[2*w+1] + bbv[2*w+1];
    outv[w] = (unsigned)f2bf(y0) | ((unsigned)f2bf(y1) << 16);
  }
  *(u32x4*)(Xio + base) = outv;
}

// ---------------- fusion GEMM: out = [fwd, flip(bwd)] @ Wf^T + fb ----------------

__global__ __launch_bounds__(256, 4) void fusion_gemm(
    const unsigned short* __restrict__ Xf,   // [2*BSROWS][512] final LN outputs
    const unsigned short* __restrict__ Wf,   // [512][1024] bf16
    const float* __restrict__ fb,
    float* __restrict__ outp)
{
  __shared__ __align__(16) unsigned short As[128*64];
  __shared__ __align__(16) unsigned short Bs[64*64];

  int hw = blockIdx.x;
  int lg = (hw & 7)*256 + (hw >> 3);   // 2048 blocks
  int nt = lg & 7;
  int mt = lg >> 3;                    // 0..255

  const int tid = threadIdx.x;
  const int lane = tid & 63;
  const int wv = tid >> 6;
  const int n0 = nt*64;
  const int lrow  = lane >> 3;
  const int slotp = (lane & 7) ^ (lrow & 7);

  f32x4 acc[2][4];
  #pragma unroll
  for (int i=0;i<2;++i)
    #pragma unroll
    for (int j=0;j<4;++j) acc[i][j] = (f32x4)(0.f);

  for (int ks=0; ks<16; ++ks){
    int k0 = ks*64;
    const unsigned short* Abase = Xf + ((k0 >= 512) ? (size_t)BSROWS*512 : 0);
    int kc = k0 & 511;
    int flip = (k0 >= 512) ? 4095 : 0;
    #pragma unroll
    for (int it=0; it<4; ++it){
      int row = it*32 + wv*8 + lrow;
      int sr = (mt*128 + row) ^ flip;        // flip s within batch for bwd half
      gload_lds16(Abase + (size_t)sr*512 + kc + slotp*8,
                  As + (it*32 + wv*8)*64);
    }
    #pragma unroll
    for (int it=0; it<2; ++it){
      int row = it*32 + wv*8 + lrow;
      gload_lds16(Wf + (size_t)(n0 + row)*1024 + k0 + slotp*8,
                  Bs + (it*32 + wv*8)*64);
    }
    __syncthreads();
    #pragma unroll
    for (int kk=0; kk<2; ++kk){
      int kslot = kk*4 + (lane >> 4);
      u32x4 af[2];
      #pragma unroll
      for (int mf=0; mf<2; ++mf){
        int row = wv*32 + mf*16 + (lane & 15);
        af[mf] = *(const u32x4*)(As + row*64 + ((kslot ^ (row&7))<<3));
      }
      #pragma unroll
      for (int nf=0; nf<4; ++nf){
        int row = nf*16 + (lane & 15);
        u32x4 bv = *(const u32x4*)(Bs + row*64 + ((kslot ^ (row&7))<<3));
        #pragma unroll
        for (int mf=0; mf<2; ++mf) mfma_bf16(acc[mf][nf], af[mf], bv);
      }
    }
    __syncthreads();
  }
  mfma_fence();

  #pragma unroll
  for (int nf=0; nf<4; ++nf){
    int col = n0 + nf*16 + (lane & 15);
    float bias = fb[col];
    #pragma unroll
    for (int mf=0; mf<2; ++mf){
      int rb = mt*128 + wv*32 + mf*16 + ((lane>>4)<<2);
      #pragma unroll
      for (int r=0; r<4; ++r)
        outp[(size_t)(rb + r)*512 + col] = acc[mf][nf][r] + bias;
    }
  }
}

// ---------------- launch ----------------

extern "C" void kernel_launch(void* const* d_in, const int* in_sizes, int n_in,
                              void* d_out, int out_size, void* d_ws, size_t ws_size,
                              hipStream_t stream)
{
  (void)in_sizes; (void)n_in; (void)out_size; (void)ws_size;
  const float* x   = (const float*)d_in[0];
  const float* wzf = (const float*)d_in[1];
  const float* bzf = (const float*)d_in[2];
  const float* whf = (const float*)d_in[3];
  const float* bhf = (const float*)d_in[4];
  const float* wzb = (const float*)d_in[5];
  const float* bzb = (const float*)d_in[6];
  const float* whb = (const float*)d_in[7];
  const float* bhb = (const float*)d_in[8];
  const float* fw  = (const float*)d_in[9];
  const float* fbb = (const float*)d_in[10];
  const float* lng = (const float*)d_in[11];
  const float* lnb = (const float*)d_in[12];
  float* outp = (float*)d_out;

  // ws layout (~140 MiB; r2's profile proves ws >= ~171 MiB):
  char* ws = (char*)d_ws;
  size_t o = 0;
  unsigned short* Wbf = (unsigned short*)(ws + o); o += (size_t)16*512*512*2;   // 8 MiB
  unsigned short* Wfb = (unsigned short*)(ws + o); o += (size_t)512*1024*2;     // 1 MiB
  unsigned short* X   = (unsigned short*)(ws + o); o += (size_t)2*BSROWS*512*2; // 64 MiB
  unsigned int*   PH0 = (unsigned int*)  (ws + o); o += (size_t)BSROWS*512*4;   // 64 MiB
  float* Aagg = (float*)(ws + o); o += (size_t)CGALL*NCHUNK*4;                  // 1 MiB
  float* Bagg = (float*)(ws + o); o += (size_t)CGALL*NCHUNK*4;
  float* Hin  = (float*)(ws + o); o += (size_t)CGALL*NCHUNK*4;
  // dir-1 PH lives in d_out (exactly BSROWS*512*4 = 64 MiB); fully
  // overwritten before any read each call; fusion writes final out last.
  unsigned int* PH1 = (unsigned int*)d_out;

  prep_all<<<10496, 256, 0, stream>>>(wzf, whf, wzb, whb, fw, x, Wbf, Wfb, X);

  for (int l = 0; l < NLAYER; ++l){
    // l==0: both dirs read the pristine dir-0 panel (dir1 row-flipped).
    int xoff1 = (l == 0) ? 0 : BSROWS;
    int flip1 = (l == 0) ? 4095 : 0;
    gate_gemm_scan<<<4096, 256, 0, stream>>>(X, Wbf, bzf, bhf, bzb, bhb,
                                             PH0, PH1, Aagg, Bagg, l, xoff1, flip1);
    scan_p2 <<<CGALL/256, 256, 0, stream>>>(Aagg, Bagg, Hin);
    recon_ln<<<16384, 256, 0, stream>>>(PH0, PH1, Hin, X, lng, lnb, l > 0 ? 1 : 0);
  }

  fusion_gemm<<<2048, 256, 0, stream>>>(X, Wfb, fbb, outp);
}